// Round 12
// baseline (158.284 us; speedup 1.0000x reference)
//
#include <hip/hip_runtime.h>
#include <hip/hip_bf16.h>

// GINConv: out = relu(((1+eps)x + scatter_sum(x[src]->dst)) @ W1 + b1) @ W2 + b2
#define N_NODES 50000
#define F_IN    128
#define F_HID   512
#define N_EDGES 800000

// Coarse buckets: 64 nodes/bucket. ATOMIC-FREE fill: fixed per-(block,bucket) cells
// entries[bkt][196][32]; producer uses only LDS atomics + plain stores (no memset, no
// global atomics). Consumer scans its bucket's 196x32 strip (coalesced, count-guarded).
// gin_fused (1 block/bucket, 512 thr): LDS slot-binning -> branchless-8 register gather
// (sentinel rows, index prefetch) -> 64-row MFMA MLP.
#define NBKT 782          // ceil(50000/64)
#define NFB  196          // fill blocks: ceil(800000/4096), 4 edges/thread @1024 thr
#define CCAP 32           // per-(block,bucket) cell cap; lambda=5.24, P(>=32)~2e-15
#define NDMAX 64          // per-node slot cap; deg lambda=16, P(>64)~1e-18
#define NZERO 50000       // sentinel row index; row 50000 zeroed in fill_prep

typedef __bf16 bf16x4 __attribute__((ext_vector_type(4)));
typedef __bf16 bf16x8 __attribute__((ext_vector_type(8)));
typedef float  f32x4  __attribute__((ext_vector_type(4)));
typedef unsigned short u16x8 __attribute__((ext_vector_type(8)));

// ---------------- fill_prep: atomic-free edge fill || x->bf16 || W -> B-frag order -----
// B-fragment layout (HW-verified): lane holds B[k=(lane>>4)*8+j][n=lane&15].
#define NB_X 1563           // 1,600,000 float4 / 1024
#define NB_W 8              // 8192 fragment-slots / 1024, per weight matrix
__global__ __launch_bounds__(1024) void fill_prep(const float* __restrict__ x,
                                                  const int* __restrict__ ei,
                                                  const float* __restrict__ W1,
                                                  const float* __restrict__ W2,
                                                  __bf16* __restrict__ xb,
                                                  __bf16* __restrict__ w1f,
                                                  __bf16* __restrict__ w2f,
                                                  int* __restrict__ cntmat,
                                                  int* __restrict__ entries) {
    int b = blockIdx.x, tid = threadIdx.x;
    if (b < NFB) {
        __shared__ int hist[NBKT];
        for (int i = tid; i < NBKT; i += 1024) hist[i] = 0;
        __syncthreads();

        int e0 = (b * 1024 + tid) * 4;
        int bk[4], sl[4], pay[4];
        bool act[4];
        #pragma unroll
        for (int k = 0; k < 4; ++k) {
            int e = e0 + k;
            act[k] = (e < N_EDGES);
            if (act[k]) {
                int src = ei[e];
                int dst = ei[N_EDGES + e];
                bk[k] = dst >> 6;
                pay[k] = ((dst & 63) << 16) | src;         // src < 65536
                sl[k] = atomicAdd(&hist[bk[k]], 1);        // LDS-only atomic
            }
        }
        __syncthreads();

        // publish per-(block,bucket) counts: contiguous stores, covers every cell
        for (int i = tid; i < NBKT; i += 1024)
            cntmat[(size_t)b * NBKT + i] = hist[i];

        // scatter into fixed cells (no reservation needed)
        #pragma unroll
        for (int k = 0; k < 4; ++k)
            if (act[k] && sl[k] < CCAP)
                entries[((size_t)bk[k] * NFB + b) * CCAP + sl[k]] = pay[k];
    } else if (b < NFB + NB_X) {
        int i = (b - NFB) * 1024 + tid;                    // 1,600,000 float4s
        if (i < 1600000) {
            float4 v = ((const float4*)x)[i];
            bf16x4 o = {(__bf16)v.x, (__bf16)v.y, (__bf16)v.z, (__bf16)v.w};
            ((bf16x4*)xb)[i] = o;
        }
    } else if (b < NFB + NB_X + NB_W) {
        int t = (b - NFB - NB_X) * 1024 + tid;
        int lane = t & 63, kk = (t >> 6) & 3, nt = (t >> 8) & 7, c = (t >> 11) & 3;
        int q = lane >> 4, l16 = lane & 15;
        bf16x8 o;
        #pragma unroll
        for (int j = 0; j < 8; ++j)
            o[j] = (__bf16)W1[(kk * 32 + q * 8 + j) * F_HID + c * 128 + nt * 16 + l16];
        *(bf16x8*)(w1f + (size_t)t * 8) = o;
    } else if (b < NFB + NB_X + 2 * NB_W) {
        int t = (b - NFB - NB_X - NB_W) * 1024 + tid;
        int lane = t & 63, kk = (t >> 6) & 3, nt = (t >> 8) & 7, c = (t >> 11) & 3;
        int q = lane >> 4, l16 = lane & 15;
        bf16x8 o;
        #pragma unroll
        for (int j = 0; j < 8; ++j)
            o[j] = (__bf16)W2[(c * 128 + kk * 32 + q * 8 + j) * F_IN + nt * 16 + l16];
        *(bf16x8*)(w2f + (size_t)t * 8) = o;
    } else {
        if (tid < 16) {                                    // zero sentinel row 50000
            uint4 z = {0, 0, 0, 0};
            ((uint4*)(xb + (size_t)NZERO * F_IN))[tid] = z;
        }
    }
}

// ---------------- gin_fused: strip-scan bin -> pipelined gather -> MFMA MLP ------------
// One block (512 thr, 8 waves) per bucket. NO min-waves clause (R4: forced occupancy
// spilled to scratch, +72MB HBM writes).
// Phase 0: bin16 pre-filled with NZERO (sentinel -> zero row); scan the bucket's
//          196x32 entry strip (coalesced, guarded by per-block counts); LDS-push;
//          slot (p&3)*16+(p>>2) makes each quad's indices CONTIGUOUS in bin16.
// Phase 1: wave handles 8 nodes; 8 UNCONDITIONAL independent row-loads per node (dead
//          slots hit the L1-hot zero row); next node's index vectors prefetched while
//          rows fly. Masked tail only for deg>32. shfl-reduce; A-tile to LDS, swizzled.
// Phase 2: 64-row MFMA: wave=(wr,wc); H via 16KB LDS (unioned over phase-0 state).
__global__ __launch_bounds__(512) void gin_fused(const __bf16* __restrict__ xb,
                                                 const int* __restrict__ cntmat,
                                                 const int* __restrict__ entries,
                                                 const float* __restrict__ eps,
                                                 const __bf16* __restrict__ w1f,
                                                 const __bf16* __restrict__ w2f,
                                                 const float* __restrict__ b1,
                                                 const float* __restrict__ b2,
                                                 float* __restrict__ out) {
    // {degs,bin16} dead after phase 1; Hb first written in phase 2 (barrier between).
    __shared__ union __attribute__((aligned(16))) {
        struct { int degs[64]; unsigned short bin16[64 * NDMAX]; } p0;   // 8.25 KB
        __bf16 Hb[8192];                                                 // 16 KB
    } u;
    __shared__ __attribute__((aligned(16))) __bf16 As[8192];   // 16 KB A-tile, swizzled
    __shared__ int cnts[NFB];

    const int tid = threadIdx.x;
    const int wave = tid >> 6, lane = tid & 63;
    const int q = lane >> 4, l16 = lane & 15;
    const int bkt = blockIdx.x;

    // ---- phase 0: sentinel-fill bin16, zero degs, strip-scan into per-node slots ----
    if (tid < 64) u.p0.degs[tid] = 0;
    {
        const int zz = (NZERO << 16) | NZERO;    // 0xC350C350: two sentinel u16 slots
        int* b32 = (int*)u.p0.bin16;             // 2048 ints
        #pragma unroll
        for (int k = 0; k < 4; ++k) b32[tid * 4 + k] = zz;
    }
    if (tid < NFB) {
        int c = cntmat[(size_t)tid * NBKT + bkt];
        cnts[tid] = c < CCAP ? c : CCAP;
    }
    __syncthreads();

    {
        const int* strip = entries + (size_t)bkt * NFB * CCAP;
        for (int j = tid; j < NFB * CCAP; j += 512) {
            int b = j >> 5, s = j & (CCAP - 1);
            if (s < cnts[b]) {
                int en = strip[j];
                int dl = en >> 16;
                int p = atomicAdd(&u.p0.degs[dl], 1);
                if (p < NDMAX)
                    u.p0.bin16[dl * NDMAX + (p & 3) * 16 + (p >> 2)] =
                        (unsigned short)(en & 0xffff);
            }
        }
    }
    __syncthreads();

    // ---- phase 1: software-pipelined branchless-8 register gather ----
    const float s = 1.0f + eps[0];
#define ROW(idx) (*(const bf16x8*)(xb + (size_t)(idx) * F_IN + l16 * 8))
    const int nb0 = (wave * 8) * NDMAX + q * 16;
    u16x8 cI0 = *(const u16x8*)&u.p0.bin16[nb0];
    u16x8 cI1 = *(const u16x8*)&u.p0.bin16[nb0 + 8];
    int   cdg = u.p0.degs[wave * 8];
    #pragma unroll
    for (int t = 0; t < 8; ++t) {
        int n = wave * 8 + t;
        int node = bkt * 64 + n;

        // 8 unconditional independent row-loads (slots beyond count hit the zero row)
        bf16x8 ra0 = ROW(cI0[0]), ra1 = ROW(cI0[1]), ra2 = ROW(cI0[2]), ra3 = ROW(cI0[3]);
        bf16x8 rb0 = ROW(cI0[4]), rb1 = ROW(cI0[5]), rb2 = ROW(cI0[6]), rb3 = ROW(cI0[7]);

        // prefetch next node's index vectors + degree while the rows are in flight
        u16x8 nI0, nI1;
        int ndg = 0;
        if (t < 7) {
            nI0 = *(const u16x8*)&u.p0.bin16[nb0 + (t + 1) * NDMAX];
            nI1 = *(const u16x8*)&u.p0.bin16[nb0 + (t + 1) * NDMAX + 8];
            ndg = u.p0.degs[n + 1];
        }

        float acc[8];
        #pragma unroll
        for (int i = 0; i < 8; ++i) acc[i] = 0.0f;
        if (q == 0) {
            bf16x8 self = ROW(node < N_NODES ? node : NZERO);
            #pragma unroll
            for (int i = 0; i < 8; ++i) acc[i] = (float)self[i] * s;
        }

        #pragma unroll
        for (int i = 0; i < 8; ++i)
            acc[i] += ((float)ra0[i] + (float)ra1[i]) + ((float)ra2[i] + (float)ra3[i]);
        #pragma unroll
        for (int i = 0; i < 8; ++i)
            acc[i] += ((float)rb0[i] + (float)rb1[i]) + ((float)rb2[i] + (float)rb3[i]);

        int dg = cdg < NDMAX ? cdg : NDMAX;
        int myc = (dg + 3 - q) >> 2;                  // this quad's entry count (p%4==q)
        if (myc > 8) {                                // deg>32 tail: rare, serial ok
            #pragma unroll
            for (int v = 0; v < 8; ++v)
                if (myc > 8 + v) {
                    bf16x8 r = ROW(cI1[v]);
                    #pragma unroll
                    for (int i = 0; i < 8; ++i) acc[i] += (float)r[i];
                }
        }

        #pragma unroll
        for (int i = 0; i < 8; ++i) {
            acc[i] += __shfl_xor(acc[i], 16);
            acc[i] += __shfl_xor(acc[i], 32);
        }
        if (lane < 16) {
            bf16x8 o;
            #pragma unroll
            for (int i = 0; i < 8; ++i) o[i] = (__bf16)acc[i];
            int byte_ = ((n >> 4) * 16 + lane) * 256 + (n & 15) * 16;
            byte_ ^= (lane & 7) << 4;
            *(bf16x8*)((char*)As + byte_) = o;
        }

        if (t < 7) { cI0 = nI0; cI1 = nI1; cdg = ndg; }
    }
    __syncthreads();

    // ---- phase 2: 64-row MFMA MLP ----
    const int wr = wave >> 2, wc = wave & 3;

    f32x4 acc_o[2][2];
    #pragma unroll
    for (int ni = 0; ni < 2; ++ni) {
        float bv = b2[wc * 32 + ni * 16 + l16];
        f32x4 b4 = {bv, bv, bv, bv};
        acc_o[0][ni] = b4;
        acc_o[1][ni] = b4;
    }

    for (int c = 0; c < 4; ++c) {
        f32x4 acc_h[2][2];
        #pragma unroll
        for (int ni = 0; ni < 2; ++ni) {
            float bv = b1[c * 128 + wc * 32 + ni * 16 + l16];
            f32x4 b4 = {bv, bv, bv, bv};
            acc_h[0][ni] = b4;
            acc_h[1][ni] = b4;
        }
        #pragma unroll
        for (int kk = 0; kk < 4; ++kk) {
            bf16x8 am[2], bw[2];
            #pragma unroll
            for (int mi = 0; mi < 2; ++mi) {
                int g = wr * 2 + mi;
                int byte_ = ((g * 4 + kk) * 4 + q) * 256 + l16 * 16;
                byte_ ^= ((kk * 4 + q) & 7) << 4;
                am[mi] = *(const bf16x8*)((const char*)As + byte_);
            }
            #pragma unroll
            for (int ni = 0; ni < 2; ++ni)
                bw[ni] = *(const bf16x8*)(w1f +
                    ((size_t)((c * 8 + wc * 2 + ni) * 4 + kk) << 9) + lane * 8);
            #pragma unroll
            for (int mi = 0; mi < 2; ++mi)
                #pragma unroll
                for (int ni = 0; ni < 2; ++ni)
                    acc_h[mi][ni] = __builtin_amdgcn_mfma_f32_16x16x32_bf16(
                        am[mi], bw[ni], acc_h[mi][ni], 0, 0, 0);
        }
        // relu -> Hb in A-frag order: C elem (row=wr*32+mi*16+q*4+r, col=wc*32+ni*16+l16)
        #pragma unroll
        for (int mi = 0; mi < 2; ++mi) {
            int g = wr * 2 + mi;
            #pragma unroll
            for (int ni = 0; ni < 2; ++ni)
                #pragma unroll
                for (int r = 0; r < 4; ++r)
                    u.Hb[(((g * 4 + wc) * 64 + (ni * 2 + (l16 >> 3)) * 16 + q * 4 + r) << 3)
                         + (l16 & 7)] = (__bf16)fmaxf(acc_h[mi][ni][r], 0.0f);
        }
        __syncthreads();

        #pragma unroll
        for (int kk = 0; kk < 4; ++kk) {
            bf16x8 am[2], bw[2];
            #pragma unroll
            for (int mi = 0; mi < 2; ++mi)
                am[mi] = *(const bf16x8*)&u.Hb[(((wr * 2 + mi) * 4 + kk) * 64 + lane) << 3];
            #pragma unroll
            for (int ni = 0; ni < 2; ++ni)
                bw[ni] = *(const bf16x8*)(w2f +
                    ((size_t)((c * 8 + wc * 2 + ni) * 4 + kk) << 9) + lane * 8);
            #pragma unroll
            for (int mi = 0; mi < 2; ++mi)
                #pragma unroll
                for (int ni = 0; ni < 2; ++ni)
                    acc_o[mi][ni] = __builtin_amdgcn_mfma_f32_16x16x32_bf16(
                        am[mi], bw[ni], acc_o[mi][ni], 0, 0, 0);
        }
        __syncthreads();
    }

    const int m0 = bkt * 64;
    #pragma unroll
    for (int mi = 0; mi < 2; ++mi)
        #pragma unroll
        for (int ni = 0; ni < 2; ++ni)
            #pragma unroll
            for (int r = 0; r < 4; ++r) {
                int m = m0 + wr * 32 + mi * 16 + q * 4 + r;
                if (m < N_NODES)
                    out[(size_t)m * F_IN + wc * 32 + ni * 16 + l16] = acc_o[mi][ni][r];
            }
}

extern "C" void kernel_launch(void* const* d_in, const int* in_sizes, int n_in,
                              void* d_out, int out_size, void* d_ws, size_t ws_size,
                              hipStream_t stream) {
    const float* x   = (const float*)d_in[0];
    const int*   ei  = (const int*)d_in[1];
    const float* W1  = (const float*)d_in[2];
    const float* b1  = (const float*)d_in[3];
    const float* W2  = (const float*)d_in[4];
    const float* b2  = (const float*)d_in[5];
    const float* eps = (const float*)d_in[6];
    float* out = (float*)d_out;

    // ws layout (~33.8 MB):
    char* ws = (char*)d_ws;
    __bf16* xb     = (__bf16*)ws;                  // 50048 rows * 256 B = 12,812,288 B
    __bf16* w1f    = (__bf16*)(ws + 12900000);     // 131,072 B
    __bf16* w2f    = (__bf16*)(ws + 13100000);     // 131,072 B
    int*    cntmat = (int*)(ws + 13300000);        // 196*782*4 B = 613,088 B
    int*    entries = (int*)(ws + 14000000);       // 782*196*32*4 B = 19,616,256 B

    fill_prep<<<NFB + NB_X + 2 * NB_W + 1, 1024, 0, stream>>>(x, ei, W1, W2,
                                                              xb, w1f, w2f,
                                                              cntmat, entries);
    gin_fused<<<NBKT, 512, 0, stream>>>(xb, cntmat, entries, eps, w1f, w2f, b1, b2, out);
}

// Round 14
// 152.231 us; speedup vs baseline: 1.0398x; 1.0398x over previous
//
#include <hip/hip_runtime.h>
#include <hip/hip_bf16.h>

// GINConv: out = relu(((1+eps)x + scatter_sum(x[src]->dst)) @ W1 + b1) @ W2 + b2
#define N_NODES 50000
#define F_IN    128
#define F_HID   512
#define N_EDGES 800000

// Coarse buckets: 64 nodes/bucket. ATOMIC-FREE fill: fixed per-(block,bucket) cells
// entries[bkt][196][32]; producer uses only LDS atomics + plain stores (no memset, no
// global atomics). Consumer: per-cell EXACT drain (reads only the ~1024 valid entries;
// R12's full strip scan cost +10us). NO grid-wide sync anywhere (R10 coop launch
// silently no-ops in this harness; R13 software barrier hangs).
// gin_fused (1 block/bucket, 512 thr): LDS slot-binning -> branchless-8 register gather
// (sentinel rows, index prefetch) -> 64-row MFMA MLP.
#define NBKT 782          // ceil(50000/64)
#define NFB  196          // fill blocks: ceil(800000/4096), 4 edges/thread @1024 thr
#define CCAP 32           // per-(block,bucket) cell cap; lambda=5.24, P(>=32)~2e-15
#define NDMAX 64          // per-node slot cap; deg lambda=16, P(>64)~1e-18
#define NZERO 50000       // sentinel row index; row 50000 zeroed in fill_prep

typedef __bf16 bf16x4 __attribute__((ext_vector_type(4)));
typedef __bf16 bf16x8 __attribute__((ext_vector_type(8)));
typedef float  f32x4  __attribute__((ext_vector_type(4)));
typedef unsigned short u16x8 __attribute__((ext_vector_type(8)));

// ---------------- fill_prep: atomic-free edge fill || x->bf16 || W -> B-frag order -----
// B-fragment layout (HW-verified): lane holds B[k=(lane>>4)*8+j][n=lane&15].
#define NB_X 1563           // 1,600,000 float4 / 1024
#define NB_W 8              // 8192 fragment-slots / 1024, per weight matrix
__global__ __launch_bounds__(1024) void fill_prep(const float* __restrict__ x,
                                                  const int* __restrict__ ei,
                                                  const float* __restrict__ W1,
                                                  const float* __restrict__ W2,
                                                  __bf16* __restrict__ xb,
                                                  __bf16* __restrict__ w1f,
                                                  __bf16* __restrict__ w2f,
                                                  int* __restrict__ cntmat,
                                                  int* __restrict__ entries) {
    int b = blockIdx.x, tid = threadIdx.x;
    if (b < NFB) {
        __shared__ int hist[NBKT];
        for (int i = tid; i < NBKT; i += 1024) hist[i] = 0;
        __syncthreads();

        int e0 = (b * 1024 + tid) * 4;
        int bk[4], sl[4], pay[4];
        bool act[4];
        #pragma unroll
        for (int k = 0; k < 4; ++k) {
            int e = e0 + k;
            act[k] = (e < N_EDGES);
            if (act[k]) {
                int src = ei[e];
                int dst = ei[N_EDGES + e];
                bk[k] = dst >> 6;
                pay[k] = ((dst & 63) << 16) | src;         // src < 65536
                sl[k] = atomicAdd(&hist[bk[k]], 1);        // LDS-only atomic
            }
        }
        __syncthreads();

        // publish per-(block,bucket) counts: contiguous stores, covers every cell
        for (int i = tid; i < NBKT; i += 1024)
            cntmat[(size_t)b * NBKT + i] = hist[i];

        // scatter into fixed cells (no reservation needed)
        #pragma unroll
        for (int k = 0; k < 4; ++k)
            if (act[k] && sl[k] < CCAP)
                entries[((size_t)bk[k] * NFB + b) * CCAP + sl[k]] = pay[k];
    } else if (b < NFB + NB_X) {
        int i = (b - NFB) * 1024 + tid;                    // 1,600,000 float4s
        if (i < 1600000) {
            float4 v = ((const float4*)x)[i];
            bf16x4 o = {(__bf16)v.x, (__bf16)v.y, (__bf16)v.z, (__bf16)v.w};
            ((bf16x4*)xb)[i] = o;
        }
    } else if (b < NFB + NB_X + NB_W) {
        int t = (b - NFB - NB_X) * 1024 + tid;
        int lane = t & 63, kk = (t >> 6) & 3, nt = (t >> 8) & 7, c = (t >> 11) & 3;
        int q = lane >> 4, l16 = lane & 15;
        bf16x8 o;
        #pragma unroll
        for (int j = 0; j < 8; ++j)
            o[j] = (__bf16)W1[(kk * 32 + q * 8 + j) * F_HID + c * 128 + nt * 16 + l16];
        *(bf16x8*)(w1f + (size_t)t * 8) = o;
    } else if (b < NFB + NB_X + 2 * NB_W) {
        int t = (b - NFB - NB_X - NB_W) * 1024 + tid;
        int lane = t & 63, kk = (t >> 6) & 3, nt = (t >> 8) & 7, c = (t >> 11) & 3;
        int q = lane >> 4, l16 = lane & 15;
        bf16x8 o;
        #pragma unroll
        for (int j = 0; j < 8; ++j)
            o[j] = (__bf16)W2[(c * 128 + kk * 32 + q * 8 + j) * F_IN + nt * 16 + l16];
        *(bf16x8*)(w2f + (size_t)t * 8) = o;
    } else {
        if (tid < 16) {                                    // zero sentinel row 50000
            uint4 z = {0, 0, 0, 0};
            ((uint4*)(xb + (size_t)NZERO * F_IN))[tid] = z;
        }
    }
}

// ---------------- gin_fused: exact-drain bin -> pipelined gather -> MFMA MLP -----------
// One block (512 thr, 8 waves) per bucket. NO min-waves clause (R4: forced occupancy
// spilled to scratch, +72MB HBM writes).
// Phase 0: bin16 pre-filled with NZERO (sentinel -> zero row); thread t<196 drains its
//          own cell exactly (first 8 entries prefetched as 2x int4 - cells contiguous;
//          tail loop for the ~9% of cells with cnt>8). LDS-push; slot (p&3)*16+(p>>2)
//          makes each quad's indices CONTIGUOUS in bin16.
// Phase 1: wave handles 8 nodes; 8 UNCONDITIONAL independent row-loads per node (dead
//          slots hit the L1-hot zero row); next node's index vectors prefetched while
//          rows fly. Masked tail only for deg>32. shfl-reduce; A-tile to LDS, swizzled.
// Phase 2: 64-row MFMA: wave=(wr,wc); H via 16KB LDS (unioned over phase-0 state).
__global__ __launch_bounds__(512) void gin_fused(const __bf16* __restrict__ xb,
                                                 const int* __restrict__ cntmat,
                                                 const int* __restrict__ entries,
                                                 const float* __restrict__ eps,
                                                 const __bf16* __restrict__ w1f,
                                                 const __bf16* __restrict__ w2f,
                                                 const float* __restrict__ b1,
                                                 const float* __restrict__ b2,
                                                 float* __restrict__ out) {
    // {degs,bin16} dead after phase 1; Hb first written in phase 2 (barrier between).
    __shared__ union __attribute__((aligned(16))) {
        struct { int degs[64]; unsigned short bin16[64 * NDMAX]; } p0;   // 8.25 KB
        __bf16 Hb[8192];                                                 // 16 KB
    } u;
    __shared__ __attribute__((aligned(16))) __bf16 As[8192];   // 16 KB A-tile, swizzled

    const int tid = threadIdx.x;
    const int wave = tid >> 6, lane = tid & 63;
    const int q = lane >> 4, l16 = lane & 15;
    const int bkt = blockIdx.x;

    // ---- phase 0: sentinel-fill bin16, zero degs, per-cell exact drain ----
    if (tid < 64) u.p0.degs[tid] = 0;
    {
        const int zz = (NZERO << 16) | NZERO;    // 0xC350C350: two sentinel u16 slots
        int* b32 = (int*)u.p0.bin16;             // 2048 ints
        #pragma unroll
        for (int k = 0; k < 4; ++k) b32[tid * 4 + k] = zz;
    }
    __syncthreads();

    if (tid < NFB) {
        int cnt = cntmat[(size_t)tid * NBKT + bkt];
        cnt = cnt < CCAP ? cnt : CCAP;
        const int* cell = entries + ((size_t)bkt * NFB + tid) * CCAP;
        // branchless prefetch of the first 8 entries (cell is contiguous, always valid)
        int4 e0 = ((const int4*)cell)[0];
        int4 e1 = ((const int4*)cell)[1];
        int ebuf[8] = {e0.x, e0.y, e0.z, e0.w, e1.x, e1.y, e1.z, e1.w};
        #pragma unroll
        for (int s = 0; s < 8; ++s)
            if (s < cnt) {
                int en = ebuf[s];
                int dl = en >> 16;
                int p = atomicAdd(&u.p0.degs[dl], 1);
                if (p < NDMAX)
                    u.p0.bin16[dl * NDMAX + (p & 3) * 16 + (p >> 2)] =
                        (unsigned short)(en & 0xffff);
            }
        for (int s = 8; s < cnt; ++s) {          // ~9% of cells
            int en = cell[s];
            int dl = en >> 16;
            int p = atomicAdd(&u.p0.degs[dl], 1);
            if (p < NDMAX)
                u.p0.bin16[dl * NDMAX + (p & 3) * 16 + (p >> 2)] =
                    (unsigned short)(en & 0xffff);
        }
    }
    __syncthreads();

    // ---- phase 1: software-pipelined branchless-8 register gather ----
    const float s = 1.0f + eps[0];
#define ROW(idx) (*(const bf16x8*)(xb + (size_t)(idx) * F_IN + l16 * 8))
    const int nb0 = (wave * 8) * NDMAX + q * 16;
    u16x8 cI0 = *(const u16x8*)&u.p0.bin16[nb0];
    u16x8 cI1 = *(const u16x8*)&u.p0.bin16[nb0 + 8];
    int   cdg = u.p0.degs[wave * 8];
    #pragma unroll
    for (int t = 0; t < 8; ++t) {
        int n = wave * 8 + t;
        int node = bkt * 64 + n;

        // 8 unconditional independent row-loads (slots beyond count hit the zero row)
        bf16x8 ra0 = ROW(cI0[0]), ra1 = ROW(cI0[1]), ra2 = ROW(cI0[2]), ra3 = ROW(cI0[3]);
        bf16x8 rb0 = ROW(cI0[4]), rb1 = ROW(cI0[5]), rb2 = ROW(cI0[6]), rb3 = ROW(cI0[7]);

        // prefetch next node's index vectors + degree while the rows are in flight
        u16x8 nI0, nI1;
        int ndg = 0;
        if (t < 7) {
            nI0 = *(const u16x8*)&u.p0.bin16[nb0 + (t + 1) * NDMAX];
            nI1 = *(const u16x8*)&u.p0.bin16[nb0 + (t + 1) * NDMAX + 8];
            ndg = u.p0.degs[n + 1];
        }

        float acc[8];
        #pragma unroll
        for (int i = 0; i < 8; ++i) acc[i] = 0.0f;
        if (q == 0) {
            bf16x8 self = ROW(node < N_NODES ? node : NZERO);
            #pragma unroll
            for (int i = 0; i < 8; ++i) acc[i] = (float)self[i] * s;
        }

        #pragma unroll
        for (int i = 0; i < 8; ++i)
            acc[i] += ((float)ra0[i] + (float)ra1[i]) + ((float)ra2[i] + (float)ra3[i]);
        #pragma unroll
        for (int i = 0; i < 8; ++i)
            acc[i] += ((float)rb0[i] + (float)rb1[i]) + ((float)rb2[i] + (float)rb3[i]);

        int dg = cdg < NDMAX ? cdg : NDMAX;
        int myc = (dg + 3 - q) >> 2;                  // this quad's entry count (p%4==q)
        if (myc > 8) {                                // deg>32 tail: rare, serial ok
            #pragma unroll
            for (int v = 0; v < 8; ++v)
                if (myc > 8 + v) {
                    bf16x8 r = ROW(cI1[v]);
                    #pragma unroll
                    for (int i = 0; i < 8; ++i) acc[i] += (float)r[i];
                }
        }

        #pragma unroll
        for (int i = 0; i < 8; ++i) {
            acc[i] += __shfl_xor(acc[i], 16);
            acc[i] += __shfl_xor(acc[i], 32);
        }
        if (lane < 16) {
            bf16x8 o;
            #pragma unroll
            for (int i = 0; i < 8; ++i) o[i] = (__bf16)acc[i];
            int byte_ = ((n >> 4) * 16 + lane) * 256 + (n & 15) * 16;
            byte_ ^= (lane & 7) << 4;
            *(bf16x8*)((char*)As + byte_) = o;
        }

        if (t < 7) { cI0 = nI0; cI1 = nI1; cdg = ndg; }
    }
    __syncthreads();

    // ---- phase 2: 64-row MFMA MLP ----
    const int wr = wave >> 2, wc = wave & 3;

    f32x4 acc_o[2][2];
    #pragma unroll
    for (int ni = 0; ni < 2; ++ni) {
        float bv = b2[wc * 32 + ni * 16 + l16];
        f32x4 b4 = {bv, bv, bv, bv};
        acc_o[0][ni] = b4;
        acc_o[1][ni] = b4;
    }

    for (int c = 0; c < 4; ++c) {
        f32x4 acc_h[2][2];
        #pragma unroll
        for (int ni = 0; ni < 2; ++ni) {
            float bv = b1[c * 128 + wc * 32 + ni * 16 + l16];
            f32x4 b4 = {bv, bv, bv, bv};
            acc_h[0][ni] = b4;
            acc_h[1][ni] = b4;
        }
        #pragma unroll
        for (int kk = 0; kk < 4; ++kk) {
            bf16x8 am[2], bw[2];
            #pragma unroll
            for (int mi = 0; mi < 2; ++mi) {
                int g = wr * 2 + mi;
                int byte_ = ((g * 4 + kk) * 4 + q) * 256 + l16 * 16;
                byte_ ^= ((kk * 4 + q) & 7) << 4;
                am[mi] = *(const bf16x8*)((const char*)As + byte_);
            }
            #pragma unroll
            for (int ni = 0; ni < 2; ++ni)
                bw[ni] = *(const bf16x8*)(w1f +
                    ((size_t)((c * 8 + wc * 2 + ni) * 4 + kk) << 9) + lane * 8);
            #pragma unroll
            for (int mi = 0; mi < 2; ++mi)
                #pragma unroll
                for (int ni = 0; ni < 2; ++ni)
                    acc_h[mi][ni] = __builtin_amdgcn_mfma_f32_16x16x32_bf16(
                        am[mi], bw[ni], acc_h[mi][ni], 0, 0, 0);
        }
        // relu -> Hb in A-frag order: C elem (row=wr*32+mi*16+q*4+r, col=wc*32+ni*16+l16)
        #pragma unroll
        for (int mi = 0; mi < 2; ++mi) {
            int g = wr * 2 + mi;
            #pragma unroll
            for (int ni = 0; ni < 2; ++ni)
                #pragma unroll
                for (int r = 0; r < 4; ++r)
                    u.Hb[(((g * 4 + wc) * 64 + (ni * 2 + (l16 >> 3)) * 16 + q * 4 + r) << 3)
                         + (l16 & 7)] = (__bf16)fmaxf(acc_h[mi][ni][r], 0.0f);
        }
        __syncthreads();

        #pragma unroll
        for (int kk = 0; kk < 4; ++kk) {
            bf16x8 am[2], bw[2];
            #pragma unroll
            for (int mi = 0; mi < 2; ++mi)
                am[mi] = *(const bf16x8*)&u.Hb[(((wr * 2 + mi) * 4 + kk) * 64 + lane) << 3];
            #pragma unroll
            for (int ni = 0; ni < 2; ++ni)
                bw[ni] = *(const bf16x8*)(w2f +
                    ((size_t)((c * 8 + wc * 2 + ni) * 4 + kk) << 9) + lane * 8);
            #pragma unroll
            for (int mi = 0; mi < 2; ++mi)
                #pragma unroll
                for (int ni = 0; ni < 2; ++ni)
                    acc_o[mi][ni] = __builtin_amdgcn_mfma_f32_16x16x32_bf16(
                        am[mi], bw[ni], acc_o[mi][ni], 0, 0, 0);
        }
        __syncthreads();
    }

    const int m0 = bkt * 64;
    #pragma unroll
    for (int mi = 0; mi < 2; ++mi)
        #pragma unroll
        for (int ni = 0; ni < 2; ++ni)
            #pragma unroll
            for (int r = 0; r < 4; ++r) {
                int m = m0 + wr * 32 + mi * 16 + q * 4 + r;
                if (m < N_NODES)
                    out[(size_t)m * F_IN + wc * 32 + ni * 16 + l16] = acc_o[mi][ni][r];
            }
}

extern "C" void kernel_launch(void* const* d_in, const int* in_sizes, int n_in,
                              void* d_out, int out_size, void* d_ws, size_t ws_size,
                              hipStream_t stream) {
    const float* x   = (const float*)d_in[0];
    const int*   ei  = (const int*)d_in[1];
    const float* W1  = (const float*)d_in[2];
    const float* b1  = (const float*)d_in[3];
    const float* W2  = (const float*)d_in[4];
    const float* b2  = (const float*)d_in[5];
    const float* eps = (const float*)d_in[6];
    float* out = (float*)d_out;

    // ws layout (~33.8 MB):
    char* ws = (char*)d_ws;
    __bf16* xb     = (__bf16*)ws;                  // 50048 rows * 256 B = 12,812,288 B
    __bf16* w1f    = (__bf16*)(ws + 12900000);     // 131,072 B
    __bf16* w2f    = (__bf16*)(ws + 13100000);     // 131,072 B
    int*    cntmat = (int*)(ws + 13300000);        // 196*782*4 B = 613,088 B
    int*    entries = (int*)(ws + 14000000);       // 782*196*32*4 B = 19,616,256 B

    fill_prep<<<NFB + NB_X + 2 * NB_W + 1, 1024, 0, stream>>>(x, ei, W1, W2,
                                                              xb, w1f, w2f,
                                                              cntmat, entries);
    gin_fused<<<NBKT, 512, 0, stream>>>(xb, cntmat, entries, eps, w1f, w2f, b1, b2, out);
}